// Round 1
// baseline (1211.830 us; speedup 1.0000x reference)
//
#include <hip/hip_runtime.h>
#include <hip/hip_bf16.h>

#define NU 100000
#define NI 100000
#define NE 1600000
#define KIN 128
#define KOUT 64

// ---------- order-preserving float<->uint key for atomicMax on float ----------
__device__ __forceinline__ unsigned fkey(float f) {
    unsigned u = __float_as_uint(f);
    return (u & 0x80000000u) ? ~u : (u | 0x80000000u);
}
__device__ __forceinline__ float funkey(unsigned k) {
    return (k & 0x80000000u) ? __uint_as_float(k ^ 0x80000000u) : __uint_as_float(~k);
}

// ---------- fused linear: Wh = A@W + b, plus su = Wh.a_src, sd = Wh.a_dst ----------
// block = 256 threads; thread t -> row r = t>>4 (0..15), col-group k4 = t&15 (float4 of cols)
__global__ __launch_bounds__(256) void linear_attn_kernel(
    const float* __restrict__ A,    // M x 128
    const float* __restrict__ W,    // 128 x 64
    const float* __restrict__ bvec, // 64
    const float* __restrict__ attn, // 128 = [a_src(64) | a_dst(64)]
    float* __restrict__ Wh,         // M x 64
    float* __restrict__ s_src,      // M
    float* __restrict__ s_dst,      // M
    int M)
{
    __shared__ float4 Wl[128 * 16];   // [kk][k4]  32 KB
    __shared__ float  Al[16 * 132];   // 16 rows padded to 132 (bank-conflict-free broadcast)
    __shared__ float  bl[64];
    __shared__ float  asrc[64], adst[64];

    int t = threadIdx.x;
    for (int i = t; i < 128 * 16; i += 256) Wl[i] = ((const float4*)W)[i];
    if (t < 64) { bl[t] = bvec[t]; asrc[t] = attn[t]; adst[t] = attn[64 + t]; }
    __syncthreads();

    int r  = t >> 4;
    int k4 = t & 15;
    int nChunks = M / 16;   // M = 100000 -> 6250 exactly
    for (int c = blockIdx.x; c < nChunks; c += gridDim.x) {
        const float4* Ag = (const float4*)(A + (size_t)c * 16 * 128);
        __syncthreads();   // protect Al against readers from previous chunk
        for (int i = t; i < 512; i += 256) {   // 512 float4 = 16x128 floats
            float4 v = Ag[i];
            int rr = i >> 5;            // row within tile
            int cc = (i & 31) * 4;      // col within row
            float* dp = &Al[rr * 132 + cc];
            dp[0] = v.x; dp[1] = v.y; dp[2] = v.z; dp[3] = v.w;
        }
        __syncthreads();

        float4 acc = {0.f, 0.f, 0.f, 0.f};
        const float* arow = &Al[r * 132];
        #pragma unroll 8
        for (int kk = 0; kk < 128; kk++) {
            float a = arow[kk];
            float4 w = Wl[kk * 16 + k4];
            acc.x += a * w.x; acc.y += a * w.y; acc.z += a * w.z; acc.w += a * w.w;
        }
        acc.x += bl[k4 * 4 + 0]; acc.y += bl[k4 * 4 + 1];
        acc.z += bl[k4 * 4 + 2]; acc.w += bl[k4 * 4 + 3];

        int row = c * 16 + r;
        ((float4*)(Wh + (size_t)row * KOUT))[k4] = acc;

        // attention dots (reduce 16 lanes that share row r)
        float p1 = acc.x * asrc[k4*4] + acc.y * asrc[k4*4+1] + acc.z * asrc[k4*4+2] + acc.w * asrc[k4*4+3];
        float p2 = acc.x * adst[k4*4] + acc.y * adst[k4*4+1] + acc.z * adst[k4*4+2] + acc.w * adst[k4*4+3];
        #pragma unroll
        for (int off = 8; off; off >>= 1) {
            p1 += __shfl_down(p1, off);
            p2 += __shfl_down(p2, off);
        }
        if (k4 == 0) { s_src[row] = p1; s_dst[row] = p2; }
    }
}

// ---------- edge pass 1: segment max (atomicMax on flipped-uint keys) ----------
__global__ __launch_bounds__(256) void edge_max_kernel(
    const int* __restrict__ src, const int* __restrict__ dst,
    const float* __restrict__ ssrc, const float* __restrict__ sdst,
    unsigned* __restrict__ m, int nE)
{
    int i = blockIdx.x * 256 + threadIdx.x;
    if (i >= nE) return;
    int s = src[i], d = dst[i];
    float e = ssrc[s] + sdst[d];
    e = e > 0.f ? e : 0.01f * e;
    atomicMax(&m[d], fkey(e));
}

// ---------- edge pass 2: segment sum of exp(e - m) ----------
__global__ __launch_bounds__(256) void edge_sum_kernel(
    const int* __restrict__ src, const int* __restrict__ dst,
    const float* __restrict__ ssrc, const float* __restrict__ sdst,
    const unsigned* __restrict__ m, float* __restrict__ ssum, int nE)
{
    int i = blockIdx.x * 256 + threadIdx.x;
    if (i >= nE) return;
    int s = src[i], d = dst[i];
    float e = ssrc[s] + sdst[d];
    e = e > 0.f ? e : 0.01f * e;
    float ex = __expf(e - funkey(m[d]));
    unsafeAtomicAdd(&ssum[d], ex);
}

// ---------- edge pass 3: h[dst] += alpha * Wh_src[src], one wave per edge ----------
__global__ __launch_bounds__(256) void edge_agg_kernel(
    const int* __restrict__ src, const int* __restrict__ dst,
    const float* __restrict__ ssrc, const float* __restrict__ sdst,
    const unsigned* __restrict__ m, const float* __restrict__ ssum,
    const float* __restrict__ Whs, float* __restrict__ h, int nE)
{
    int lane = threadIdx.x & 63;
    int wave = blockIdx.x * 4 + (threadIdx.x >> 6);
    int nW = gridDim.x * 4;
    for (int e = wave; e < nE; e += nW) {
        int s = src[e], d = dst[e];
        float ev = ssrc[s] + sdst[d];
        ev = ev > 0.f ? ev : 0.01f * ev;
        float alpha = __expf(ev - funkey(m[d])) / ssum[d];
        float v = alpha * Whs[(size_t)s * KOUT + lane];
        unsafeAtomicAdd(&h[(size_t)d * KOUT + lane], v);
    }
}

extern "C" void kernel_launch(void* const* d_in, const int* in_sizes, int n_in,
                              void* d_out, int out_size, void* d_ws, size_t ws_size,
                              hipStream_t stream)
{
    const float* feat_user = (const float*)d_in[0];
    const float* feat_item = (const float*)d_in[1];
    const float* W_user    = (const float*)d_in[2];
    const float* b_user    = (const float*)d_in[3];
    const float* W_item    = (const float*)d_in[4];
    const float* b_item    = (const float*)d_in[5];
    const float* attn_w    = (const float*)d_in[6];
    const int*   src_u2i   = (const int*)d_in[7];
    const int*   dst_u2i   = (const int*)d_in[8];
    const int*   src_i2u   = (const int*)d_in[9];
    const int*   dst_i2u   = (const int*)d_in[10];

    float* out    = (float*)d_out;
    float* h_user = out;                         // NU x 64
    float* h_item = out + (size_t)NU * KOUT;     // NI x 64

    // workspace layout (floats): 13.6M floats = 54.4 MB
    float*    ws      = (float*)d_ws;
    float*    Wh_user = ws;
    float*    Wh_item = Wh_user + (size_t)NU * KOUT;
    float*    su_user = Wh_item + (size_t)NI * KOUT;
    float*    sd_user = su_user + NU;
    float*    su_item = sd_user + NU;
    float*    sd_item = su_item + NI;
    unsigned* m_item  = (unsigned*)(sd_item + NI);
    float*    s_item  = (float*)(m_item + NI);
    unsigned* m_user  = (unsigned*)(s_item + NI);
    float*    s_user  = (float*)(m_user + NU);

    // zero-init: output accumulators, m keys (0 == -inf in key space), sums
    hipMemsetAsync(d_out, 0, (size_t)out_size * sizeof(float), stream);
    hipMemsetAsync(m_item, 0, (size_t)(NI + NI + NU + NU) * sizeof(float), stream);

    linear_attn_kernel<<<2048, 256, 0, stream>>>(feat_user, W_user, b_user, attn_w,
                                                 Wh_user, su_user, sd_user, NU);
    linear_attn_kernel<<<2048, 256, 0, stream>>>(feat_item, W_item, b_item, attn_w,
                                                 Wh_item, su_item, sd_item, NI);

    int eb = (NE + 255) / 256;
    edge_max_kernel<<<eb, 256, 0, stream>>>(src_u2i, dst_u2i, su_user, sd_item, m_item, NE);
    edge_max_kernel<<<eb, 256, 0, stream>>>(src_i2u, dst_i2u, su_item, sd_user, m_user, NE);
    edge_sum_kernel<<<eb, 256, 0, stream>>>(src_u2i, dst_u2i, su_user, sd_item, m_item, s_item, NE);
    edge_sum_kernel<<<eb, 256, 0, stream>>>(src_i2u, dst_i2u, su_item, sd_user, m_user, s_user, NE);
    edge_agg_kernel<<<40000, 256, 0, stream>>>(src_u2i, dst_u2i, su_user, sd_item,
                                               m_item, s_item, Wh_user, h_item, NE);
    edge_agg_kernel<<<40000, 256, 0, stream>>>(src_i2u, dst_i2u, su_item, sd_user,
                                               m_user, s_user, Wh_item, h_user, NE);
}

// Round 2
// 823.740 us; speedup vs baseline: 1.4711x; 1.4711x over previous
//
#include <hip/hip_runtime.h>
#include <hip/hip_bf16.h>

#define NU 100000
#define NI 100000
#define NE 1600000
#define KIN 128
#define KOUT 64

// ---------- bf16 pack/unpack (round-to-nearest-even) ----------
__device__ __forceinline__ unsigned short f2bf(float f) {
    unsigned u = __float_as_uint(f);
    unsigned r = (u + 0x7fffu + ((u >> 16) & 1u)) >> 16;
    return (unsigned short)r;
}
__device__ __forceinline__ float bf2f(unsigned short h) {
    return __uint_as_float(((unsigned)h) << 16);
}

// ---------- fused linear: Wh = A@W + b (stored bf16), su = Wh.a_src, sd = Wh.a_dst ----------
__global__ __launch_bounds__(256) void linear_attn_kernel(
    const float* __restrict__ A,    // M x 128
    const float* __restrict__ W,    // 128 x 64
    const float* __restrict__ bvec, // 64
    const float* __restrict__ attn, // 128 = [a_src(64) | a_dst(64)]
    unsigned short* __restrict__ Wh,// M x 64 (bf16)
    float* __restrict__ s_src,      // M
    float* __restrict__ s_dst,      // M
    int M)
{
    __shared__ float4 Wl[128 * 16];   // [kk][k4]  32 KB
    __shared__ float  Al[16 * 132];   // 16 rows padded
    __shared__ float  bl[64];
    __shared__ float  asrc[64], adst[64];

    int t = threadIdx.x;
    for (int i = t; i < 128 * 16; i += 256) Wl[i] = ((const float4*)W)[i];
    if (t < 64) { bl[t] = bvec[t]; asrc[t] = attn[t]; adst[t] = attn[64 + t]; }
    __syncthreads();

    int r  = t >> 4;
    int k4 = t & 15;
    int nChunks = M / 16;   // 6250
    for (int c = blockIdx.x; c < nChunks; c += gridDim.x) {
        const float4* Ag = (const float4*)(A + (size_t)c * 16 * 128);
        __syncthreads();
        for (int i = t; i < 512; i += 256) {
            float4 v = Ag[i];
            int rr = i >> 5;
            int cc = (i & 31) * 4;
            float* dp = &Al[rr * 132 + cc];
            dp[0] = v.x; dp[1] = v.y; dp[2] = v.z; dp[3] = v.w;
        }
        __syncthreads();

        float4 acc = {0.f, 0.f, 0.f, 0.f};
        const float* arow = &Al[r * 132];
        #pragma unroll 8
        for (int kk = 0; kk < 128; kk++) {
            float a = arow[kk];
            float4 w = Wl[kk * 16 + k4];
            acc.x += a * w.x; acc.y += a * w.y; acc.z += a * w.z; acc.w += a * w.w;
        }
        acc.x += bl[k4 * 4 + 0]; acc.y += bl[k4 * 4 + 1];
        acc.z += bl[k4 * 4 + 2]; acc.w += bl[k4 * 4 + 3];

        int row = c * 16 + r;
        ushort4 o;
        o.x = f2bf(acc.x); o.y = f2bf(acc.y); o.z = f2bf(acc.z); o.w = f2bf(acc.w);
        ((ushort4*)(Wh + (size_t)row * KOUT))[k4] = o;

        float p1 = acc.x * asrc[k4*4] + acc.y * asrc[k4*4+1] + acc.z * asrc[k4*4+2] + acc.w * asrc[k4*4+3];
        float p2 = acc.x * adst[k4*4] + acc.y * adst[k4*4+1] + acc.z * adst[k4*4+2] + acc.w * adst[k4*4+3];
        #pragma unroll
        for (int off = 8; off; off >>= 1) {
            p1 += __shfl_down(p1, off);
            p2 += __shfl_down(p2, off);
        }
        if (k4 == 0) { s_src[row] = p1; s_dst[row] = p2; }
    }
}

// ---------- CSR build: histogram of both dst arrays ----------
__global__ __launch_bounds__(256) void hist_kernel(
    const int* __restrict__ dst_u2i, const int* __restrict__ dst_i2u,
    int* __restrict__ cnt_item, int* __restrict__ cnt_user, int nE)
{
    int i = blockIdx.x * 256 + threadIdx.x;
    if (i >= nE) return;
    atomicAdd(&cnt_item[dst_u2i[i]], 1);
    atomicAdd(&cnt_user[dst_i2u[i]], 1);
}

// ---------- exclusive scan of the two count arrays (block 0: item, block 1: user) ----------
__global__ __launch_bounds__(1024) void scan2_kernel(
    const int* __restrict__ cnt_item, int* __restrict__ rp_item, int* __restrict__ cur_item,
    const int* __restrict__ cnt_user, int* __restrict__ rp_user, int* __restrict__ cur_user,
    int n)
{
    const int* cnt = blockIdx.x ? cnt_user : cnt_item;
    int* rp  = blockIdx.x ? rp_user  : rp_item;
    int* cur = blockIdx.x ? cur_user : cur_item;

    __shared__ int wsum[16];
    __shared__ int wpre[17];

    int t = threadIdx.x;
    int lane = t & 63;
    int w = t >> 6;
    int running = 0;
    int nChunks = (n + 1023) / 1024;
    for (int c = 0; c < nChunks; c++) {
        int idx = c * 1024 + t;
        int v = (idx < n) ? cnt[idx] : 0;
        int x = v;
        #pragma unroll
        for (int off = 1; off < 64; off <<= 1) {
            int y = __shfl_up(x, off);
            if (lane >= off) x += y;
        }
        if (lane == 63) wsum[w] = x;
        __syncthreads();
        if (t == 0) {
            int a = 0;
            #pragma unroll
            for (int i = 0; i < 16; i++) { wpre[i] = a; a += wsum[i]; }
            wpre[16] = a;
        }
        __syncthreads();
        int ex = running + wpre[w] + x - v;   // exclusive prefix
        if (idx < n) { rp[idx] = ex; cur[idx] = ex; }
        running += wpre[16];
        __syncthreads();
    }
    if (t == 0) rp[n] = running;
}

// ---------- scatter: sorted-by-dst source lists for both edge types ----------
__global__ __launch_bounds__(256) void scatter_kernel(
    const int* __restrict__ src_u2i, const int* __restrict__ dst_u2i,
    const int* __restrict__ src_i2u, const int* __restrict__ dst_i2u,
    int* __restrict__ cur_item, int* __restrict__ srcs_item,
    int* __restrict__ cur_user, int* __restrict__ srcs_user, int nE)
{
    int i = blockIdx.x * 256 + threadIdx.x;
    if (i >= nE) return;
    int p0 = atomicAdd(&cur_item[dst_u2i[i]], 1);
    srcs_item[p0] = src_u2i[i];
    int p1 = atomicAdd(&cur_user[dst_i2u[i]], 1);
    srcs_user[p1] = src_i2u[i];
}

// ---------- aggregation: one wave per dst node, no atomics ----------
__global__ __launch_bounds__(256) void agg_kernel(
    const int* __restrict__ rp, const int* __restrict__ srcs,
    const float* __restrict__ ssrc_arr,   // per-src-node score (Wh_src . a_src)
    const float* __restrict__ sdst_arr,   // per-dst-node score (Wh_dst . a_dst)
    const unsigned short* __restrict__ Whs, // src features, bf16, n_src x 64
    float* __restrict__ h, int nNodes)
{
    int lane = threadIdx.x & 63;
    int node = blockIdx.x * 4 + (threadIdx.x >> 6);
    if (node >= nNodes) return;

    int b = rp[node], e = rp[node + 1];
    if (b == e) {
        h[(size_t)node * KOUT + lane] = 0.f;
        return;
    }
    float sd = sdst_arr[node];

    // pass 1: segment max (lanes parallel over edges)
    float mx = -3.4e38f;
    for (int j = b + lane; j < e; j += 64) {
        float ev = ssrc_arr[srcs[j]] + sd;
        ev = ev > 0.f ? ev : 0.01f * ev;
        mx = fmaxf(mx, ev);
    }
    #pragma unroll
    for (int off = 32; off; off >>= 1) mx = fmaxf(mx, __shfl_xor(mx, off));

    // pass 2: wave-wide per edge — accumulate exp-weighted rows + denominator
    float acc = 0.f, ssum = 0.f;
    int j = b;
    for (; j + 1 < e; j += 2) {
        int s0 = srcs[j], s1 = srcs[j + 1];
        float ev0 = ssrc_arr[s0] + sd; ev0 = ev0 > 0.f ? ev0 : 0.01f * ev0;
        float ev1 = ssrc_arr[s1] + sd; ev1 = ev1 > 0.f ? ev1 : 0.01f * ev1;
        float w0 = __expf(ev0 - mx), w1 = __expf(ev1 - mx);
        float f0 = bf2f(Whs[(size_t)s0 * KOUT + lane]);
        float f1 = bf2f(Whs[(size_t)s1 * KOUT + lane]);
        ssum += w0 + w1;
        acc += w0 * f0 + w1 * f1;
    }
    if (j < e) {
        int s0 = srcs[j];
        float ev0 = ssrc_arr[s0] + sd; ev0 = ev0 > 0.f ? ev0 : 0.01f * ev0;
        float w0 = __expf(ev0 - mx);
        ssum += w0;
        acc += w0 * bf2f(Whs[(size_t)s0 * KOUT + lane]);
    }
    h[(size_t)node * KOUT + lane] = acc / ssum;
}

extern "C" void kernel_launch(void* const* d_in, const int* in_sizes, int n_in,
                              void* d_out, int out_size, void* d_ws, size_t ws_size,
                              hipStream_t stream)
{
    const float* feat_user = (const float*)d_in[0];
    const float* feat_item = (const float*)d_in[1];
    const float* W_user    = (const float*)d_in[2];
    const float* b_user    = (const float*)d_in[3];
    const float* W_item    = (const float*)d_in[4];
    const float* b_item    = (const float*)d_in[5];
    const float* attn_w    = (const float*)d_in[6];
    const int*   src_u2i   = (const int*)d_in[7];
    const int*   dst_u2i   = (const int*)d_in[8];
    const int*   src_i2u   = (const int*)d_in[9];
    const int*   dst_i2u   = (const int*)d_in[10];

    float* out    = (float*)d_out;
    float* h_user = out;
    float* h_item = out + (size_t)NU * KOUT;

    // workspace layout
    char* p = (char*)d_ws;
    unsigned short* Wh_user = (unsigned short*)p; p += (size_t)NU * KOUT * 2;   // 12.8 MB
    unsigned short* Wh_item = (unsigned short*)p; p += (size_t)NI * KOUT * 2;   // 12.8 MB
    float* su_user = (float*)p; p += NU * 4;
    float* sd_user = (float*)p; p += NU * 4;
    float* su_item = (float*)p; p += NI * 4;
    float* sd_item = (float*)p; p += NI * 4;
    int* cnt_item  = (int*)p; p += NI * 4;      // memset together (contiguous)
    int* cnt_user  = (int*)p; p += NU * 4;
    int* rp_item   = (int*)p; p += (NI + 1) * 4;
    int* rp_user   = (int*)p; p += (NU + 1) * 4;
    int* cur_item  = (int*)p; p += NI * 4;
    int* cur_user  = (int*)p; p += NU * 4;
    int* srcs_item = (int*)p; p += (size_t)NE * 4;   // 6.4 MB
    int* srcs_user = (int*)p; p += (size_t)NE * 4;   // 6.4 MB

    hipMemsetAsync(cnt_item, 0, (size_t)(NI + NU) * 4, stream);

    int eb = (NE + 255) / 256;
    hist_kernel<<<eb, 256, 0, stream>>>(dst_u2i, dst_i2u, cnt_item, cnt_user, NE);
    scan2_kernel<<<2, 1024, 0, stream>>>(cnt_item, rp_item, cur_item,
                                         cnt_user, rp_user, cur_user, NI);
    scatter_kernel<<<eb, 256, 0, stream>>>(src_u2i, dst_u2i, src_i2u, dst_i2u,
                                           cur_item, srcs_item, cur_user, srcs_user, NE);

    linear_attn_kernel<<<2048, 256, 0, stream>>>(feat_user, W_user, b_user, attn_w,
                                                 Wh_user, su_user, sd_user, NU);
    linear_attn_kernel<<<2048, 256, 0, stream>>>(feat_item, W_item, b_item, attn_w,
                                                 Wh_item, su_item, sd_item, NI);

    agg_kernel<<<(NI + 3) / 4, 256, 0, stream>>>(rp_item, srcs_item, su_user, sd_item,
                                                 Wh_user, h_item, NI);
    agg_kernel<<<(NU + 3) / 4, 256, 0, stream>>>(rp_user, srcs_user, su_item, sd_user,
                                                 Wh_item, h_user, NU);
}